// Round 10
// baseline (565.385 us; speedup 1.0000x reference)
//
#include <hip/hip_runtime.h>
#include <cstdint>
#include <cstddef>

using u16 = unsigned short;
typedef short short8 __attribute__((ext_vector_type(8)));
typedef unsigned short us8 __attribute__((ext_vector_type(8)));
typedef unsigned short us4 __attribute__((ext_vector_type(4)));
typedef unsigned short us2 __attribute__((ext_vector_type(2)));
typedef float f32x4 __attribute__((ext_vector_type(4)));
typedef float f4 __attribute__((ext_vector_type(4)));

#define T_ 1024
#define B_ 8
#define H_ 1024
#define HEADS_ 16
#define HD_ 64
#define N3_ 3072

__device__ __forceinline__ float b2f(u16 u){
  union { float f; unsigned int i; } v; v.i = ((unsigned int)u) << 16; return v.f;
}
// fast bf16 convert: round-half-up
__device__ __forceinline__ u16 f2b(float f){
  union { float f; unsigned int i; } v; v.f = f;
  return (u16)((v.i + 0x8000u) >> 16);
}

// ---------------- GEMM (unchanged from passing rounds) ----------------
template<bool HAS_S, bool SCALE_A, bool POS_A, bool A_BF16, bool OUT_F32>
__global__ __launch_bounds__(256) void k_gemm(const void* __restrict__ A_, const float* __restrict__ W,
                                              const float* __restrict__ RA, const float* __restrict__ S,
                                              const float* __restrict__ bias, void* __restrict__ C_, int N){
  const int K = 1024;
  const int n0 = blockIdx.x * 128, m0 = blockIdx.y * 128;
  const int tid = threadIdx.x, lane = tid & 63;
  const int wave = tid >> 6, wr = wave >> 1, wc = wave & 1;
  __shared__ alignas(16) u16 At[128 * 32];
  __shared__ alignas(16) u16 Bt[128 * 32];
  f32x4 acc[4][4] = {};

  for (int kt = 0; kt < 32; ++kt){
    const int k0 = kt * 32;
    f4 wv[4];
    us8 avb[2];
    f4 avf[4];
#pragma unroll
    for (int i = 0; i < 4; ++i){
      int c = tid + i * 256, r = c >> 3, sg = c & 7;
      wv[i] = *(const f4*)(W + (size_t)(n0 + r) * K + k0 + sg * 4);
    }
    if (A_BF16){
      const u16* A = (const u16*)A_;
#pragma unroll
      for (int i = 0; i < 2; ++i){
        int c = tid + i * 256, r = c >> 2, sg = c & 3;
        avb[i] = *(const us8*)(A + (size_t)(m0 + r) * K + k0 + sg * 8);
      }
    } else {
      const float* A = (const float*)A_;
#pragma unroll
      for (int i = 0; i < 4; ++i){
        int c = tid + i * 256, r = c >> 3, sg = c & 7;
        int m = m0 + r;
        const float* ap = POS_A ? (A + (size_t)(m >> 3) * K + k0 + sg * 4)
                                : (A + (size_t)m * K + k0 + sg * 4);
        avf[i] = *(const f4*)ap;
        if (SCALE_A){
          f4 rv = *(const f4*)(RA + (m & 7) * K + k0 + sg * 4);
          avf[i] = avf[i] * rv;
        }
      }
    }
    __syncthreads();
#pragma unroll
    for (int i = 0; i < 4; ++i){
      int c = tid + i * 256, r = c >> 3, sg = c & 7;
      us4 pw;
#pragma unroll
      for (int u = 0; u < 4; ++u) pw[u] = f2b(wv[i][u]);
      *(us4*)(Bt + r * 32 + sg * 4) = pw;
    }
    if (A_BF16){
#pragma unroll
      for (int i = 0; i < 2; ++i){
        int c = tid + i * 256, r = c >> 2, sg = c & 3;
        *(us8*)(At + r * 32 + sg * 8) = avb[i];
      }
    } else {
#pragma unroll
      for (int i = 0; i < 4; ++i){
        int c = tid + i * 256, r = c >> 3, sg = c & 7;
        us4 pa;
#pragma unroll
        for (int u = 0; u < 4; ++u) pa[u] = f2b(avf[i][u]);
        *(us4*)(At + r * 32 + sg * 4) = pa;
      }
    }
    __syncthreads();
    short8 af[4], bf[4];
#pragma unroll
    for (int i = 0; i < 4; ++i){
      int ar = wr * 64 + i * 16 + (lane & 15);
      af[i] = *(const short8*)(At + ar * 32 + ((lane >> 4) << 3));
      int br = wc * 64 + i * 16 + (lane & 15);
      bf[i] = *(const short8*)(Bt + br * 32 + ((lane >> 4) << 3));
    }
#pragma unroll
    for (int i = 0; i < 4; ++i)
#pragma unroll
      for (int j = 0; j < 4; ++j)
        acc[i][j] = __builtin_amdgcn_mfma_f32_16x16x32_bf16(af[i], bf[j], acc[i][j], 0, 0, 0);
  }
#pragma unroll
  for (int i = 0; i < 4; ++i){
    int row0 = wr * 64 + i * 16 + ((lane >> 4) << 2);
#pragma unroll
    for (int j = 0; j < 4; ++j){
      int o = n0 + wc * 64 + j * 16 + (lane & 15);
      float bv = bias[o];
#pragma unroll
      for (int jj = 0; jj < 4; ++jj){
        int m = m0 + row0 + jj;
        float v = acc[i][j][jj];
        if (HAS_S) v *= S[(m & 7) * N + o];
        v += bv;
        if (OUT_F32) ((float*)C_)[(size_t)m * N + o] = v;
        else         ((u16*)C_)[(size_t)m * N + o] = f2b(v);
      }
    }
  }
}

// ---------------- V transpose to global: VT[n][d][t] <- qkv[t, b, head*192+128+d] ----------------
__global__ __launch_bounds__(256) void k_vt(const u16* __restrict__ qkv, u16* __restrict__ VT){
  const int tt = blockIdx.x;
  const int n = blockIdx.y;
  const int b = n >> 4, head = n & 15;
  __shared__ alignas(16) u16 tile[64][72];
  const int tid = threadIdx.x;
#pragma unroll
  for (int i = 0; i < 2; ++i){
    int c = tid + i * 256;
    int r = c >> 3, sg = c & 7;
    const u16* src = qkv + ((size_t)(tt * 64 + r) * 8 + b) * N3_ + head * 192 + 128 + sg * 8;
    *(us8*)&tile[r][sg * 8] = *(const us8*)src;
  }
  __syncthreads();
#pragma unroll
  for (int i = 0; i < 2; ++i){
    int c = tid + i * 256;
    int d = c >> 3, sg = c & 7;
    us8 ov;
#pragma unroll
    for (int u = 0; u < 8; ++u) ov[u] = tile[sg * 8 + u][d];
    *(us8*)(VT + ((size_t)n * 64 + d) * 1024 + tt * 64 + sg * 8) = ov;
  }
}

// ---------------- fused attention, q-tile = 16 ----------------
// grid 8192, XCD-swizzled: xcd=bid&7, qb=(bid>>3)&63, n=(bid&7)+((bid>>9)<<3).
// No LDS staging of K/rk/V (per-XCD working set = one n = 384KB, L2-resident).
// q-tile 16 cuts per-thread registers (p 32 f32, Oacc 16 f32) so the kernel fits the
// 128-reg budget of 4 waves/EU (amdgpu_waves_per_eu(4)) without scratch OR AGPR spill.
#define G_OFF   0           // flat g: 17*1025*2 = 34850 B; later per-wave Pt/partials (8 x 4KB)
#define RWQ_OFF 34880       // 16 x 128B
#define RRQ_OFF 36928       // 32 x 128B (rows 17..31 only feed discarded MFMA lanes)
#define RED_OFF 41024       // 256 floats: [0:128) row-max, [128:256) row-L
#define SMEM_SZ 42048

__device__ __forceinline__ int gswz(int byt){ return byt ^ (((byt >> 13) & 3) << 5); }

__global__ __launch_bounds__(512) __attribute__((amdgpu_waves_per_eu(4)))
void k_attn(const u16* __restrict__ qkv, const u16* __restrict__ rk,
            const u16* __restrict__ VTg, const float* __restrict__ rwb,
            const float* __restrict__ rrb, u16* __restrict__ ctx){
  const int bid = blockIdx.x;
  const int n = (bid & 7) + ((bid >> 9) << 3);
  const int qb = (bid >> 3) & 63;
  const int q0 = qb * 16;
  const int bat = n >> 4, head = n & 15;
  const int tid = threadIdx.x, lane = tid & 63, wave = tid >> 6;
  const int l15 = lane & 15, grp = lane >> 4;

  __shared__ alignas(16) char smem[SMEM_SZ];
  char* gB  = smem + G_OFF;
  u16* rwq = (u16*)(smem + RWQ_OFF);
  u16* rrq = (u16*)(smem + RRQ_OFF);
  float* redf = (float*)(smem + RED_OFF);

  // ---- Phase A: rw_q (16 rows) + rr_q (32 rows; 17 meaningful), bias, prescale 0.125*log2e
  const float PRESCALE = 0.125f * 1.44269504089f;
  {
    int c = tid;
    if (c < 384){
      int s = c >> 3, sg = c & 7;
      u16* dst; int row; const float* bias;
      if (s < 16){ dst = rwq; row = s; bias = rwb; }
      else       { dst = rrq; row = s - 16; bias = rrb; }
      int qrow = q0 + row;
      float v[8];
      const float* bp2 = bias + head * 64 + sg * 8;
      if (qrow < T_){
        const u16* qp = qkv + ((size_t)qrow * 8 + bat) * N3_ + head * 192 + sg * 8;
        us8 qv = *(const us8*)qp;
        f4 b0 = *(const f4*)bp2, b1 = *(const f4*)(bp2 + 4);
#pragma unroll
        for (int u = 0; u < 4; ++u){
          v[u]     = (b2f(qv[u])     + b0[u]) * PRESCALE;
          v[u + 4] = (b2f(qv[u + 4]) + b1[u]) * PRESCALE;
        }
      } else {
#pragma unroll
        for (int u = 0; u < 8; ++u) v[u] = 0.f;
      }
      us8 pk;
#pragma unroll
      for (int u = 0; u < 8; ++u) pk[u] = f2b(v[u]);
      *(us8*)((char*)dst + row * 128 + ((sg * 16) ^ ((row & 7) << 4))) = pk;
    }
  }
  if (tid < 17) *(u16*)(gB + gswz(tid * 2050 + 2048)) = 0;

  auto ldf = [&](const void* base, int row, int kkb)->short8 {
    int co = kkb + (grp << 4);
    return *(const short8*)((const char*)base + row * 128 + (co ^ ((row & 7) << 4)));
  };

  __syncthreads();                 // (1) Phase A + zero slots visible

  // ---- Phase B: g[a][r] = rr_q[q0+a].rk[r], a<17. B-frags direct from global (L2).
  {
    short8 af[2][2];
#pragma unroll
    for (int pi = 0; pi < 2; ++pi)
#pragma unroll
      for (int kk = 0; kk < 2; ++kk) af[pi][kk] = ldf(rrq, pi * 16 + l15, kk * 64);
#pragma unroll
    for (int s = 0; s < 2; ++s){
#pragma unroll
      for (int c4 = 0; c4 < 4; ++c4){
        int r = s * 512 + wave * 64 + c4 * 16 + l15;
        const u16* bp = rk + ((size_t)r * 8 + bat) * 1024 + head * 64 + grp * 8;
        short8 bf0 = *(const short8*)bp;
        short8 bf1 = *(const short8*)(bp + 32);
#pragma unroll
        for (int pi = 0; pi < 2; ++pi){
          f32x4 acc = {0.f, 0.f, 0.f, 0.f};
          acc = __builtin_amdgcn_mfma_f32_16x16x32_bf16(af[pi][0], bf0, acc, 0, 0, 0);
          acc = __builtin_amdgcn_mfma_f32_16x16x32_bf16(af[pi][1], bf1, acc, 0, 0, 0);
#pragma unroll
          for (int jj = 0; jj < 4; ++jj){
            int a = pi * 16 + (grp << 2) + jj;
            if (a < 17) *(u16*)(gB + gswz(a * 2050 + (r << 1))) = f2b(acc[jj]);
          }
        }
      }
    }
  }
  __syncthreads();                 // (2) gS complete

  // ---- Phase C: scores = AC + rel-shifted BD (branchless flat gather)
  f32x4 p[2][4];
  float pm[4] = {-3.0e38f, -3.0e38f, -3.0e38f, -3.0e38f};
  {
    short8 af[2];
#pragma unroll
    for (int kk = 0; kk < 2; ++kk) af[kk] = ldf(rwq, l15, kk * 64);
#pragma unroll
    for (int s = 0; s < 2; ++s){
#pragma unroll
      for (int c4 = 0; c4 < 4; ++c4){
        int bcol = s * 512 + wave * 64 + c4 * 16 + l15;
        const u16* kp = qkv + ((size_t)bcol * 8 + bat) * N3_ + head * 192 + 64 + grp * 8;
        short8 bf0 = *(const short8*)kp;
        short8 bf1 = *(const short8*)(kp + 32);
        f32x4 acc = {0.f, 0.f, 0.f, 0.f};
        acc = __builtin_amdgcn_mfma_f32_16x16x32_bf16(af[0], bf0, acc, 0, 0, 0);
        acc = __builtin_amdgcn_mfma_f32_16x16x32_bf16(af[1], bf1, acc, 0, 0, 0);
        int byt0 = ((1023 - q0 + bcol) << 1) + (grp << 13);
#pragma unroll
        for (int jj = 0; jj < 4; ++jj){
          int byt = byt0 + (jj << 11);
          float gv = b2f(*(const u16*)(gB + gswz(byt)));
          float sc = acc[jj] + gv;
          p[s][c4][jj] = sc;
          pm[jj] = fmaxf(pm[jj], sc);
        }
      }
    }
  }

  // ---- softmax: max reduce (rows = grp*4+jj)
#pragma unroll
  for (int jj = 0; jj < 4; ++jj)
#pragma unroll
    for (int mk = 1; mk < 16; mk <<= 1) pm[jj] = fmaxf(pm[jj], __shfl_xor(pm[jj], mk));
  if (l15 == 0){
#pragma unroll
    for (int jj = 0; jj < 4; ++jj) redf[wave * 16 + (grp << 2) + jj] = pm[jj];
  }
  __syncthreads();                 // (3) pm visible; all gS reads done (Pt overlay safe)
  float M_[4];
#pragma unroll
  for (int jj = 0; jj < 4; ++jj){
    int row = (grp << 2) + jj;
    float v = redf[row];
#pragma unroll
    for (int w = 1; w < 8; ++w) v = fmaxf(v, redf[w * 16 + row]);
    M_[jj] = v;
  }

  // ---- exp2, L accumulate, write P tile (per-wave 4KB region overlaying gS)
  char* ptW = smem + G_OFF + wave * 4096;   // [16 q][128 tl] u16, 256B rows, swizzled
  float L_[4] = {};
#pragma unroll
  for (int s = 0; s < 2; ++s)
#pragma unroll
    for (int c4 = 0; c4 < 4; ++c4)
#pragma unroll
      for (int jj = 0; jj < 4; ++jj){
        float e = __builtin_exp2f(p[s][c4][jj] - M_[jj]);
        L_[jj] += e;
        int q = (grp << 2) + jj;
        int tl = s * 64 + c4 * 16 + l15;
        *(u16*)(ptW + q * 256 + ((tl * 2) ^ ((q & 7) << 4))) = f2b(e);
      }
#pragma unroll
  for (int jj = 0; jj < 4; ++jj)
#pragma unroll
    for (int mk = 1; mk < 16; mk <<= 1) L_[jj] += __shfl_xor(L_[jj], mk);
  if (l15 == 0){
#pragma unroll
    for (int jj = 0; jj < 4; ++jj) redf[128 + wave * 16 + (grp << 2) + jj] = L_[jj];
  }
  __syncthreads();                 // (4) L + P visible

  // ---- Phase D: O = P x V. V fragments direct from global VT. Wave owns 128 t.
  f32x4 Oacc[4] = {};
#pragma unroll
  for (int s = 0; s < 2; ++s){
#pragma unroll
    for (int kk = 0; kk < 2; ++kk){
      short8 pa = *(const short8*)(ptW + l15 * 256 + ((s * 128 + kk * 64 + (grp << 4)) ^ ((l15 & 7) << 4)));
      int tg = s * 512 + wave * 64 + kk * 32 + grp * 8;
#pragma unroll
      for (int dt = 0; dt < 4; ++dt){
        int dr = dt * 16 + l15;
        short8 vb = *(const short8*)(VTg + ((size_t)n * 64 + dr) * 1024 + tg);
        Oacc[dt] = __builtin_amdgcn_mfma_f32_16x16x32_bf16(pa, vb, Oacc[dt], 0, 0, 0);
      }
    }
  }

  // ---- partials into own 4KB region (overlays own Pt; same-wave ordering), reduce
  float* par = (float*)ptW;
#pragma unroll
  for (int dt = 0; dt < 4; ++dt)
#pragma unroll
    for (int jj = 0; jj < 4; ++jj)
      par[((grp << 2) + jj) * 64 + dt * 16 + l15] = Oacc[dt][jj];
  __syncthreads();                 // (5) all partials visible
  {
    float* parAll = (float*)(smem + G_OFF);
    int q = tid >> 5, dp = (tid & 31) * 2;
    float v0 = 0.f, v1 = 0.f, sum = 0.f;
#pragma unroll
    for (int w = 0; w < 8; ++w){
      const float* pw = parAll + w * 1024 + q * 64 + dp;
      v0 += pw[0]; v1 += pw[1];
      sum += redf[128 + w * 16 + q];
    }
    float il = 1.0f / (sum + 1e-20f);
    us2 pk; pk[0] = f2b(v0 * il); pk[1] = f2b(v1 * il);
    *(us2*)(ctx + ((size_t)(q0 + q) * 8 + bat) * 1024 + head * 64 + dp) = pk;
  }
}

// ---------------- launch ----------------
extern "C" void kernel_launch(void* const* d_in, const int* in_sizes, int n_in,
                              void* d_out, int out_size, void* d_ws, size_t ws_size,
                              hipStream_t stream){
  const float* x   = (const float*)d_in[0];
  const float* pos = (const float*)d_in[1];
  const float* Wi  = (const float*)d_in[2];
  const float* bi  = (const float*)d_in[3];
  const float* Wp  = (const float*)d_in[4];
  const float* bp  = (const float*)d_in[5];
  const float* Wo  = (const float*)d_in[6];
  const float* bo  = (const float*)d_in[7];
  const float* r_i = (const float*)d_in[8];
  const float* s_i = (const float*)d_in[9];
  const float* r_p = (const float*)d_in[10];
  const float* s_p = (const float*)d_in[11];
  const float* rwb = (const float*)d_in[12];
  const float* rrb = (const float*)d_in[13];

  const size_t MB = 1024 * 1024;
  u16* qkv = (u16*)((char*)d_ws);              // 48 MiB (bf16)
  u16* rk  = (u16*)((char*)d_ws + 48 * MB);    // 16 MiB (bf16); ws total 64 MiB
  u16* VTg  = (u16*)d_out;
  u16* ctxg = (u16*)((char*)d_out + 16777216);

  k_gemm<true,  true,  false, false, false><<<dim3(24, 64), 256, 0, stream>>>(x,   Wi, r_i, s_i, bi, qkv, N3_);
  k_gemm<true,  true,  true,  false, false><<<dim3(8, 64),  256, 0, stream>>>(pos, Wp, r_p, s_p, bp, rk, 1024);
  k_vt<<<dim3(16, 128), 256, 0, stream>>>(qkv, VTg);
  k_attn<<<dim3(8192), 512, 0, stream>>>(qkv, rk, VTg, rwb, rrb, ctxg);
  hipMemcpyAsync(qkv, ctxg, (size_t)out_size * sizeof(u16), hipMemcpyDeviceToDevice, stream);
  k_gemm<false, false, false, true, true><<<dim3(8, 64), 256, 0, stream>>>(qkv, Wo, nullptr, nullptr, bo, (float*)d_out, 1024);
}

// Round 11
// 452.281 us; speedup vs baseline: 1.2501x; 1.2501x over previous
//
#include <hip/hip_runtime.h>
#include <cstdint>
#include <cstddef>

using u16 = unsigned short;
typedef short short8 __attribute__((ext_vector_type(8)));
typedef short short4v __attribute__((ext_vector_type(4)));
typedef unsigned short us8 __attribute__((ext_vector_type(8)));
typedef unsigned short us4 __attribute__((ext_vector_type(4)));
typedef float f32x4 __attribute__((ext_vector_type(4)));
typedef float f4 __attribute__((ext_vector_type(4)));

#define T_ 1024
#define B_ 8
#define H_ 1024
#define HEADS_ 16
#define HD_ 64
#define N3_ 3072

__device__ __forceinline__ float b2f(u16 u){
  union { float f; unsigned int i; } v; v.i = ((unsigned int)u) << 16; return v.f;
}
__device__ __forceinline__ u16 f2b(float f){
  union { float f; unsigned int i; } v; v.f = f;
  return (u16)((v.i + 0x8000u) >> 16);
}

// ---------------- GEMM (unchanged from passing rounds) ----------------
template<bool HAS_S, bool SCALE_A, bool POS_A, bool A_BF16, bool OUT_F32>
__global__ __launch_bounds__(256) void k_gemm(const void* __restrict__ A_, const float* __restrict__ W,
                                              const float* __restrict__ RA, const float* __restrict__ S,
                                              const float* __restrict__ bias, void* __restrict__ C_, int N){
  const int K = 1024;
  const int n0 = blockIdx.x * 128, m0 = blockIdx.y * 128;
  const int tid = threadIdx.x, lane = tid & 63;
  const int wave = tid >> 6, wr = wave >> 1, wc = wave & 1;
  __shared__ alignas(16) u16 At[128 * 32];
  __shared__ alignas(16) u16 Bt[128 * 32];
  f32x4 acc[4][4] = {};

  for (int kt = 0; kt < 32; ++kt){
    const int k0 = kt * 32;
    f4 wv[4];
    us8 avb[2];
    f4 avf[4];
#pragma unroll
    for (int i = 0; i < 4; ++i){
      int c = tid + i * 256, r = c >> 3, sg = c & 7;
      wv[i] = *(const f4*)(W + (size_t)(n0 + r) * K + k0 + sg * 4);
    }
    if (A_BF16){
      const u16* A = (const u16*)A_;
#pragma unroll
      for (int i = 0; i < 2; ++i){
        int c = tid + i * 256, r = c >> 2, sg = c & 3;
        avb[i] = *(const us8*)(A + (size_t)(m0 + r) * K + k0 + sg * 8);
      }
    } else {
      const float* A = (const float*)A_;
#pragma unroll
      for (int i = 0; i < 4; ++i){
        int c = tid + i * 256, r = c >> 3, sg = c & 7;
        int m = m0 + r;
        const float* ap = POS_A ? (A + (size_t)(m >> 3) * K + k0 + sg * 4)
                                : (A + (size_t)m * K + k0 + sg * 4);
        avf[i] = *(const f4*)ap;
        if (SCALE_A){
          f4 rv = *(const f4*)(RA + (m & 7) * K + k0 + sg * 4);
          avf[i] = avf[i] * rv;
        }
      }
    }
    __syncthreads();
#pragma unroll
    for (int i = 0; i < 4; ++i){
      int c = tid + i * 256, r = c >> 3, sg = c & 7;
      us4 pw;
#pragma unroll
      for (int u = 0; u < 4; ++u) pw[u] = f2b(wv[i][u]);
      *(us4*)(Bt + r * 32 + sg * 4) = pw;
    }
    if (A_BF16){
#pragma unroll
      for (int i = 0; i < 2; ++i){
        int c = tid + i * 256, r = c >> 2, sg = c & 3;
        *(us8*)(At + r * 32 + sg * 8) = avb[i];
      }
    } else {
#pragma unroll
      for (int i = 0; i < 4; ++i){
        int c = tid + i * 256, r = c >> 3, sg = c & 7;
        us4 pa;
#pragma unroll
        for (int u = 0; u < 4; ++u) pa[u] = f2b(avf[i][u]);
        *(us4*)(At + r * 32 + sg * 4) = pa;
      }
    }
    __syncthreads();
    short8 af[4], bf[4];
#pragma unroll
    for (int i = 0; i < 4; ++i){
      int ar = wr * 64 + i * 16 + (lane & 15);
      af[i] = *(const short8*)(At + ar * 32 + ((lane >> 4) << 3));
      int br = wc * 64 + i * 16 + (lane & 15);
      bf[i] = *(const short8*)(Bt + br * 32 + ((lane >> 4) << 3));
    }
#pragma unroll
    for (int i = 0; i < 4; ++i)
#pragma unroll
      for (int j = 0; j < 4; ++j)
        acc[i][j] = __builtin_amdgcn_mfma_f32_16x16x32_bf16(af[i], bf[j], acc[i][j], 0, 0, 0);
  }
#pragma unroll
  for (int i = 0; i < 4; ++i){
    int row0 = wr * 64 + i * 16 + ((lane >> 4) << 2);
#pragma unroll
    for (int j = 0; j < 4; ++j){
      int o = n0 + wc * 64 + j * 16 + (lane & 15);
      float bv = bias[o];
#pragma unroll
      for (int jj = 0; jj < 4; ++jj){
        int m = m0 + row0 + jj;
        float v = acc[i][j][jj];
        if (HAS_S) v *= S[(m & 7) * N + o];
        v += bv;
        if (OUT_F32) ((float*)C_)[(size_t)m * N + o] = v;
        else         ((u16*)C_)[(size_t)m * N + o] = f2b(v);
      }
    }
  }
}

// ---------------- V transpose to global: VT[n][d][t] <- qkv[t, b, head*192+128+d] ----------------
__global__ __launch_bounds__(256) void k_vt(const u16* __restrict__ qkv, u16* __restrict__ VT){
  const int tt = blockIdx.x;
  const int n = blockIdx.y;
  const int b = n >> 4, head = n & 15;
  __shared__ alignas(16) u16 tile[64][72];
  const int tid = threadIdx.x;
#pragma unroll
  for (int i = 0; i < 2; ++i){
    int c = tid + i * 256;
    int r = c >> 3, sg = c & 7;
    const u16* src = qkv + ((size_t)(tt * 64 + r) * 8 + b) * N3_ + head * 192 + 128 + sg * 8;
    *(us8*)&tile[r][sg * 8] = *(const us8*)src;
  }
  __syncthreads();
#pragma unroll
  for (int i = 0; i < 2; ++i){
    int c = tid + i * 256;
    int d = c >> 3, sg = c & 7;
    us8 ov;
#pragma unroll
    for (int u = 0; u < 8; ++u) ov[u] = tile[sg * 8 + u][d];
    *(us8*)(VT + ((size_t)n * 64 + d) * 1024 + tt * 64 + sg * 8) = ov;
  }
}

// ---------------- fused attention: q32, per-wave ONLINE softmax, swapped QK ----------------
// grid 4096, XCD swizzle. B/C operands direct from L2. Swapped QK (mfma(K,Q) -> S^T) puts
// P in the exact PV A-fragment layout: no LDS P round-trip. Online defer-max softmax per
// wave (its 128 cols); single epilogue merge. Barriers: 4 total.
#define G_OFF   0           // flat g: 33*1025*2 = 67650 B; epilogue: per-wave f32 partials (8x8KB)
#define RWQ_OFF 67664       // 32 x 128B
#define RRQ_OFF 71760       // 48 x 128B
#define RED_OFF 77904       // 512 floats: [0:256) per-wave row m, [256:512) per-wave row l
#define SMEM_SZ 79952

// swizzle: bank b0 ^= byte bit 11 (aa_0), banks b3b4 ^= byte bits 13-14 (aa bits 2-3)
__device__ __forceinline__ int gswz(int byt){
  return byt ^ (((byt >> 11) & 1) << 2) ^ (((byt >> 13) & 3) << 5);
}

__global__ __launch_bounds__(512) __attribute__((amdgpu_waves_per_eu(4)))
void k_attn(const u16* __restrict__ qkv, const u16* __restrict__ rk,
            const u16* __restrict__ VTg, const float* __restrict__ rwb,
            const float* __restrict__ rrb, u16* __restrict__ ctx){
  const int bid = blockIdx.x;
  const int n = (bid & 7) + ((bid >> 8) << 3);
  const int qb = (bid >> 3) & 31;
  const int q0 = qb * 32;
  const int bat = n >> 4, head = n & 15;
  const int tid = threadIdx.x, lane = tid & 63, wave = tid >> 6;
  const int l15 = lane & 15, grp = lane >> 4;

  __shared__ alignas(16) char smem[SMEM_SZ];
  char* gB  = smem + G_OFF;
  u16* rwq = (u16*)(smem + RWQ_OFF);
  u16* rrq = (u16*)(smem + RRQ_OFF);
  float* redf = (float*)(smem + RED_OFF);

  // ---- Phase A: rw_q (32) + rr_q (48) rows, bias, prescale 0.125*log2e
  const float PRESCALE = 0.125f * 1.44269504089f;
#pragma unroll
  for (int rep = 0; rep < 2; ++rep){
    int c = tid + rep * 512;
    if (c < 640){
      int s = c >> 3, sg = c & 7;
      u16* dst; int row; const float* bias;
      if (s < 32){ dst = rwq; row = s; bias = rwb; }
      else       { dst = rrq; row = s - 32; bias = rrb; }
      int qrow = q0 + row;
      float v[8];
      const float* bp2 = bias + head * 64 + sg * 8;
      if (qrow < T_){
        const u16* qp = qkv + ((size_t)qrow * 8 + bat) * N3_ + head * 192 + sg * 8;
        us8 qv = *(const us8*)qp;
        f4 b0 = *(const f4*)bp2, b1 = *(const f4*)(bp2 + 4);
#pragma unroll
        for (int u = 0; u < 4; ++u){
          v[u]     = (b2f(qv[u])     + b0[u]) * PRESCALE;
          v[u + 4] = (b2f(qv[u + 4]) + b1[u]) * PRESCALE;
        }
      } else {
#pragma unroll
        for (int u = 0; u < 8; ++u) v[u] = 0.f;
      }
      us8 pk;
#pragma unroll
      for (int u = 0; u < 8; ++u) pk[u] = f2b(v[u]);
      *(us8*)((char*)dst + row * 128 + ((sg * 16) ^ ((row & 7) << 4))) = pk;
    }
  }
  if (tid < 33) *(u16*)(gB + gswz(tid * 2050 + 2048)) = 0;

  auto ldf = [&](const void* base, int row, int kkb)->short8 {
    int co = kkb + (grp << 4);
    return *(const short8*)((const char*)base + row * 128 + (co ^ ((row & 7) << 4)));
  };

  __syncthreads();                 // (1) Phase A + zero slots

  // ---- Phase B: g[a][r] = rr_q[q0+a].rk[r], a<33 (normal orientation)
  {
    short8 af[3][2];
#pragma unroll
    for (int pi = 0; pi < 3; ++pi)
#pragma unroll
      for (int kk = 0; kk < 2; ++kk) af[pi][kk] = ldf(rrq, pi * 16 + l15, kk * 64);
#pragma unroll
    for (int s = 0; s < 2; ++s){
#pragma unroll
      for (int c4 = 0; c4 < 4; ++c4){
        int r = s * 512 + wave * 64 + c4 * 16 + l15;
        const u16* bp = rk + ((size_t)r * 8 + bat) * 1024 + head * 64 + grp * 8;
        short8 bf0 = *(const short8*)bp;
        short8 bf1 = *(const short8*)(bp + 32);
#pragma unroll
        for (int pi = 0; pi < 3; ++pi){
          f32x4 acc = {0.f, 0.f, 0.f, 0.f};
          acc = __builtin_amdgcn_mfma_f32_16x16x32_bf16(af[pi][0], bf0, acc, 0, 0, 0);
          acc = __builtin_amdgcn_mfma_f32_16x16x32_bf16(af[pi][1], bf1, acc, 0, 0, 0);
#pragma unroll
          for (int jj = 0; jj < 4; ++jj){
            int a = pi * 16 + (grp << 2) + jj;
            if (a < 33) *(u16*)(gB + gswz(a * 2050 + (r << 1))) = f2b(acc[jj]);
          }
        }
      }
    }
  }
  __syncthreads();                 // (2) gS complete — last barrier before epilogue

  // ---- Q fragments (B-operand of swapped QK): col=q=l15
  short8 qf[2][2];
#pragma unroll
  for (int m = 0; m < 2; ++m)
#pragma unroll
    for (int kk = 0; kk < 2; ++kk) qf[m][kk] = ldf(rwq, m * 16 + l15, kk * 64);

  // ---- online state
  float m_run[2] = {-3.0e38f, -3.0e38f};
  float l_run[2] = {0.f, 0.f};
  f32x4 Oacc[2][4] = {};

  // ---- fused score+softmax+PV over this wave's 128 cols, as 4 pairs of 16-col chunks
#pragma unroll
  for (int pr = 0; pr < 4; ++pr){
    int base = wave * 64 + (pr & 1) * 32 + (pr >> 1) * 512;
    float s_[2][2][4];             // [half][m][jj]
#pragma unroll
    for (int h = 0; h < 2; ++h){
      int cb = base + h * 16;
      const u16* kp = qkv + ((size_t)(cb + l15) * 8 + bat) * N3_ + head * 192 + 64 + grp * 8;
      short8 kf0 = *(const short8*)kp;
      short8 kf1 = *(const short8*)(kp + 32);
#pragma unroll
      for (int m = 0; m < 2; ++m){
        f32x4 acc = {0.f, 0.f, 0.f, 0.f};
        acc = __builtin_amdgcn_mfma_f32_16x16x32_bf16(kf0, qf[m][0], acc, 0, 0, 0);
        acc = __builtin_amdgcn_mfma_f32_16x16x32_bf16(kf1, qf[m][1], acc, 0, 0, 0);
        // D: row = k = grp*4+jj (within chunk), col = q = l15
        int aa = m * 16 + l15;
#pragma unroll
        for (int jj = 0; jj < 4; ++jj){
          int bcol = cb + (grp << 2) + jj;
          int byt = (aa << 11) + ((1023 - q0 + bcol) << 1);
          s_[h][m][jj] = acc[jj] + b2f(*(const u16*)(gB + gswz(byt)));
        }
      }
    }
    // pair max per q-row (q=l15): in-thread over h,jj then over grp lanes
    float cm[2];
#pragma unroll
    for (int m = 0; m < 2; ++m){
      float c0 = fmaxf(fmaxf(s_[0][m][0], s_[0][m][1]), fmaxf(s_[0][m][2], s_[0][m][3]));
      float c1 = fmaxf(fmaxf(s_[1][m][0], s_[1][m][1]), fmaxf(s_[1][m][2], s_[1][m][3]));
      float c = fmaxf(c0, c1);
      c = fmaxf(c, __shfl_xor(c, 16));
      c = fmaxf(c, __shfl_xor(c, 32));
      cm[m] = c;
    }
    // defer-max: rescale only when max grows > 8
    if (!__all(cm[0] <= m_run[0] + 8.f && cm[1] <= m_run[1] + 8.f)){
#pragma unroll
      for (int m = 0; m < 2; ++m){
        float mn = fmaxf(m_run[m], cm[m]);
        float f = __builtin_exp2f(m_run[m] - mn);
        l_run[m] *= f;
        m_run[m] = mn;
#pragma unroll
        for (int jj = 0; jj < 4; ++jj){
          float fq = __shfl(f, (lane & 48) + ((lane >> 2) & 12) + jj);
#pragma unroll
          for (int dt = 0; dt < 4; ++dt) Oacc[m][dt][jj] *= fq;
        }
      }
    }
    // exp2, accumulate l, pack P pair into K=32 A-fragment (low=half0, high=half1)
    short8 pa[2];
#pragma unroll
    for (int m = 0; m < 2; ++m){
      float ls = 0.f;
#pragma unroll
      for (int jj = 0; jj < 4; ++jj){
        float e0 = __builtin_exp2f(s_[0][m][jj] - m_run[m]);
        float e1 = __builtin_exp2f(s_[1][m][jj] - m_run[m]);
        ls += e0 + e1;
        pa[m][jj]     = (short)f2b(e0);
        pa[m][4 + jj] = (short)f2b(e1);
      }
      l_run[m] += ls;
    }
    // PV: K=32 over the 32-col pair; V slots low=cols base+grp*4, high=cols base+16+grp*4
#pragma unroll
    for (int dt = 0; dt < 4; ++dt){
      const u16* vp = VTg + ((size_t)n * 64 + dt * 16 + l15) * 1024 + base + (grp << 2);
      short4v v0 = *(const short4v*)vp;
      short4v v1 = *(const short4v*)(vp + 16);
      short8 vb = {v0[0], v0[1], v0[2], v0[3], v1[0], v1[1], v1[2], v1[3]};
#pragma unroll
      for (int m = 0; m < 2; ++m)
        Oacc[m][dt] = __builtin_amdgcn_mfma_f32_16x16x32_bf16(pa[m], vb, Oacc[m][dt], 0, 0, 0);
    }
  }

  // ---- reduce l over grp lanes; publish per-wave m,l
#pragma unroll
  for (int m = 0; m < 2; ++m){
    l_run[m] += __shfl_xor(l_run[m], 16);
    l_run[m] += __shfl_xor(l_run[m], 32);
  }
  if (grp == 0){
#pragma unroll
    for (int m = 0; m < 2; ++m){
      redf[wave * 32 + m * 16 + l15] = m_run[m];
      redf[256 + wave * 32 + m * 16 + l15] = l_run[m];
    }
  }
  __syncthreads();                 // (3) all gS gathers done -> partials may overlay gS

  // ---- per-wave O partials into own 8KB region (overlays gS)
  float* par = (float*)(smem + wave * 8192);
#pragma unroll
  for (int m = 0; m < 2; ++m)
#pragma unroll
    for (int dt = 0; dt < 4; ++dt)
#pragma unroll
      for (int jj = 0; jj < 4; ++jj)
        par[(m * 16 + (grp << 2) + jj) * 64 + dt * 16 + l15] = Oacc[m][dt][jj];
  __syncthreads();                 // (4) partials + redf visible

  // ---- merge: q = tid>>4 (32 rows), d4 = (tid&15)*4
  {
    float* parAll = (float*)smem;
    int q = tid >> 4, d4 = (tid & 15) * 4;
    float M = -3.0e38f;
#pragma unroll
    for (int w = 0; w < 8; ++w) M = fmaxf(M, redf[w * 32 + q]);
    f32x4 v = {0.f, 0.f, 0.f, 0.f};
    float L = 0.f;
#pragma unroll
    for (int w = 0; w < 8; ++w){
      float sc = __builtin_exp2f(redf[w * 32 + q] - M);
      L += redf[256 + w * 32 + q] * sc;
      f32x4 pv = *(const f32x4*)(parAll + w * 2048 + q * 64 + d4);
      v += pv * sc;
    }
    float il = 1.0f / (L + 1e-20f);
    us4 pk;
#pragma unroll
    for (int e = 0; e < 4; ++e) pk[e] = f2b(v[e] * il);
    *(us4*)(ctx + ((size_t)(q0 + q) * 8 + bat) * 1024 + head * 64 + d4) = pk;
  }
}

// ---------------- launch ----------------
extern "C" void kernel_launch(void* const* d_in, const int* in_sizes, int n_in,
                              void* d_out, int out_size, void* d_ws, size_t ws_size,
                              hipStream_t stream){
  const float* x   = (const float*)d_in[0];
  const float* pos = (const float*)d_in[1];
  const float* Wi  = (const float*)d_in[2];
  const float* bi  = (const float*)d_in[3];
  const float* Wp  = (const float*)d_in[4];
  const float* bp  = (const float*)d_in[5];
  const float* Wo  = (const float*)d_in[6];
  const float* bo  = (const float*)d_in[7];
  const float* r_i = (const float*)d_in[8];
  const float* s_i = (const float*)d_in[9];
  const float* r_p = (const float*)d_in[10];
  const float* s_p = (const float*)d_in[11];
  const float* rwb = (const float*)d_in[12];
  const float* rrb = (const float*)d_in[13];

  const size_t MB = 1024 * 1024;
  u16* qkv = (u16*)((char*)d_ws);              // 48 MiB (bf16)
  u16* rk  = (u16*)((char*)d_ws + 48 * MB);    // 16 MiB (bf16); ws total 64 MiB
  u16* VTg  = (u16*)d_out;
  u16* ctxg = (u16*)((char*)d_out + 16777216);

  k_gemm<true,  true,  false, false, false><<<dim3(24, 64), 256, 0, stream>>>(x,   Wi, r_i, s_i, bi, qkv, N3_);
  k_gemm<true,  true,  true,  false, false><<<dim3(8, 64),  256, 0, stream>>>(pos, Wp, r_p, s_p, bp, rk, 1024);
  k_vt<<<dim3(16, 128), 256, 0, stream>>>(qkv, VTg);
  k_attn<<<dim3(4096), 512, 0, stream>>>(qkv, rk, VTg, rwb, rrb, ctxg);
  hipMemcpyAsync(qkv, ctxg, (size_t)out_size * sizeof(u16), hipMemcpyDeviceToDevice, stream);
  k_gemm<false, false, false, true, true><<<dim3(8, 64), 256, 0, stream>>>(qkv, Wo, nullptr, nullptr, bo, (float*)d_out, 1024);
}

// Round 13
// 446.925 us; speedup vs baseline: 1.2651x; 1.0120x over previous
//
#include <hip/hip_runtime.h>
#include <cstdint>
#include <cstddef>

using u16 = unsigned short;
typedef short short8 __attribute__((ext_vector_type(8)));
typedef short short4v __attribute__((ext_vector_type(4)));
typedef unsigned short us8 __attribute__((ext_vector_type(8)));
typedef unsigned short us4 __attribute__((ext_vector_type(4)));
typedef float f32x4 __attribute__((ext_vector_type(4)));
typedef float f4 __attribute__((ext_vector_type(4)));

#define T_ 1024
#define B_ 8
#define H_ 1024
#define HEADS_ 16
#define HD_ 64
#define N3_ 3072

__device__ __forceinline__ float b2f(u16 u){
  union { float f; unsigned int i; } v; v.i = ((unsigned int)u) << 16; return v.f;
}
__device__ __forceinline__ u16 f2b(float f){
  union { float f; unsigned int i; } v; v.f = f;
  return (u16)((v.i + 0x8000u) >> 16);
}
typedef __attribute__((address_space(1))) const void gvoid;
typedef __attribute__((address_space(3))) void lvoid;
__device__ __forceinline__ void gload16(const void* g, void* l){
  __builtin_amdgcn_global_load_lds((gvoid*)g, (lvoid*)l, 16, 0, 0);
}

// ---------------- pre-scale+convert: Ai[m][k] = bf16(x[m][k] * r[m&7][k]) ----------------
__global__ __launch_bounds__(256) void k_scaleA(const float* __restrict__ x, const float* __restrict__ r,
                                                u16* __restrict__ o){
  int idx = blockIdx.x * 256 + threadIdx.x;
  int base = idx * 8;
  int h = base & (H_ - 1);
  int b = (base >> 10) & (B_ - 1);
  f4 x0 = *(const f4*)(x + base), x1 = *(const f4*)(x + base + 4);
  f4 r0 = *(const f4*)(r + b * H_ + h), r1 = *(const f4*)(r + b * H_ + h + 4);
  us8 ov;
#pragma unroll
  for (int u = 0; u < 4; ++u){ ov[u] = f2b(x0[u] * r0[u]); ov[u + 4] = f2b(x1[u] * r1[u]); }
  *(us8*)(o + base) = ov;
}

// ---------------- GEMM ----------------
// A_BF16: A staged via global_load_lds (16B, linear LDS). Else f32 reg-staged (+RA scale / POS broadcast).
template<bool HAS_S, bool SCALE_A, bool POS_A, bool A_BF16, bool OUT_F32>
__global__ __launch_bounds__(256) void k_gemm(const void* __restrict__ A_, const float* __restrict__ W,
                                              const float* __restrict__ RA, const float* __restrict__ S,
                                              const float* __restrict__ bias, void* __restrict__ C_, int N){
  const int K = 1024;
  const int n0 = blockIdx.x * 128, m0 = blockIdx.y * 128;
  const int tid = threadIdx.x, lane = tid & 63;
  const int wave = tid >> 6, wr = wave >> 1, wc = wave & 1;
  __shared__ alignas(16) u16 At[128 * 32];
  __shared__ alignas(16) u16 Bt[128 * 32];
  f32x4 acc[4][4] = {};

  for (int kt = 0; kt < 32; ++kt){
    const int k0 = kt * 32;
    f4 wv[4];
    f4 avf[4];
#pragma unroll
    for (int i = 0; i < 4; ++i){
      int c = tid + i * 256, r = c >> 3, sg = c & 7;
      wv[i] = *(const f4*)(W + (size_t)(n0 + r) * K + k0 + sg * 4);
    }
    if (!A_BF16){
      const float* A = (const float*)A_;
#pragma unroll
      for (int i = 0; i < 4; ++i){
        int c = tid + i * 256, r = c >> 3, sg = c & 7;
        int m = m0 + r;
        const float* ap = POS_A ? (A + (size_t)(m >> 3) * K + k0 + sg * 4)
                                : (A + (size_t)m * K + k0 + sg * 4);
        avf[i] = *(const f4*)ap;
        if (SCALE_A){
          f4 rv = *(const f4*)(RA + (m & 7) * K + k0 + sg * 4);
          avf[i] = avf[i] * rv;
        }
      }
    }
    __syncthreads();   // prior iteration's fragment reads complete
    if (A_BF16){
      const u16* A = (const u16*)A_;
#pragma unroll
      for (int i = 0; i < 2; ++i){
        int c = tid + i * 256, r = c >> 2, sg = c & 3;
        gload16(A + (size_t)(m0 + r) * K + k0 + sg * 8, (char*)At + (size_t)c * 16);
      }
    }
#pragma unroll
    for (int i = 0; i < 4; ++i){
      int c = tid + i * 256, r = c >> 3, sg = c & 7;
      us4 pw;
#pragma unroll
      for (int u = 0; u < 4; ++u) pw[u] = f2b(wv[i][u]);
      *(us4*)(Bt + r * 32 + sg * 4) = pw;
    }
    if (!A_BF16){
#pragma unroll
      for (int i = 0; i < 4; ++i){
        int c = tid + i * 256, r = c >> 3, sg = c & 7;
        us4 pa;
#pragma unroll
        for (int u = 0; u < 4; ++u) pa[u] = f2b(avf[i][u]);
        *(us4*)(At + r * 32 + sg * 4) = pa;
      }
    }
    __syncthreads();   // LDS writes (incl. global_load_lds) drained/visible
    short8 af[4], bf[4];
#pragma unroll
    for (int i = 0; i < 4; ++i){
      int ar = wr * 64 + i * 16 + (lane & 15);
      af[i] = *(const short8*)(At + ar * 32 + ((lane >> 4) << 3));
      int br = wc * 64 + i * 16 + (lane & 15);
      bf[i] = *(const short8*)(Bt + br * 32 + ((lane >> 4) << 3));
    }
#pragma unroll
    for (int i = 0; i < 4; ++i)
#pragma unroll
      for (int j = 0; j < 4; ++j)
        acc[i][j] = __builtin_amdgcn_mfma_f32_16x16x32_bf16(af[i], bf[j], acc[i][j], 0, 0, 0);
  }
#pragma unroll
  for (int i = 0; i < 4; ++i){
    int row0 = wr * 64 + i * 16 + ((lane >> 4) << 2);
#pragma unroll
    for (int j = 0; j < 4; ++j){
      int o = n0 + wc * 64 + j * 16 + (lane & 15);
      float bv = bias[o];
#pragma unroll
      for (int jj = 0; jj < 4; ++jj){
        int m = m0 + row0 + jj;
        float v = acc[i][j][jj];
        if (HAS_S) v *= S[(m & 7) * N + o];
        v += bv;
        if (OUT_F32) ((float*)C_)[(size_t)m * N + o] = v;
        else         ((u16*)C_)[(size_t)m * N + o] = f2b(v);
      }
    }
  }
}

// ---------------- V transpose to global: VT[n][d][t] <- qkv[t, b, head*192+128+d] ----------------
__global__ __launch_bounds__(256) void k_vt(const u16* __restrict__ qkv, u16* __restrict__ VT){
  const int tt = blockIdx.x;
  const int n = blockIdx.y;
  const int b = n >> 4, head = n & 15;
  __shared__ alignas(16) u16 tile[64][72];
  const int tid = threadIdx.x;
#pragma unroll
  for (int i = 0; i < 2; ++i){
    int c = tid + i * 256;
    int r = c >> 3, sg = c & 7;
    const u16* src = qkv + ((size_t)(tt * 64 + r) * 8 + b) * N3_ + head * 192 + 128 + sg * 8;
    *(us8*)&tile[r][sg * 8] = *(const us8*)src;
  }
  __syncthreads();
#pragma unroll
  for (int i = 0; i < 2; ++i){
    int c = tid + i * 256;
    int d = c >> 3, sg = c & 7;
    us8 ov;
#pragma unroll
    for (int u = 0; u < 8; ++u) ov[u] = tile[sg * 8 + u][d];
    *(us8*)(VT + ((size_t)n * 64 + d) * 1024 + tt * 64 + sg * 8) = ov;
  }
}

// ---------------- fused attention: q32, per-wave online softmax, swapped QK ----------------
// gB: flat rel-shift panel, STORE stride 1025 elem (2050 B/row), GATHER collapses to
// element aa*1024 + (1023-q0+bcol)  =>  byte aa*2048 (aa<<11). [r12 bug: used 2050 in gather]
#define G_OFF   0           // flat g: 33*1025*2 = 67650 B; epilogue: per-wave f32 partials (8x8KB)
#define RWQ_OFF 67664       // 32 x 128B
#define RRQ_OFF 71760       // 48 x 128B
#define RED_OFF 77904       // 512 floats: per-wave row m / row l
#define SMEM_SZ 79952

__global__ __launch_bounds__(512) __attribute__((amdgpu_waves_per_eu(4)))
void k_attn(const u16* __restrict__ qkv, const u16* __restrict__ rk,
            const u16* __restrict__ VTg, const float* __restrict__ rwb,
            const float* __restrict__ rrb, u16* __restrict__ ctx){
  const int bid = blockIdx.x;
  const int n = (bid & 7) + ((bid >> 8) << 3);
  const int qb = (bid >> 3) & 31;
  const int q0 = qb * 32;
  const int bat = n >> 4, head = n & 15;
  const int tid = threadIdx.x, lane = tid & 63, wave = tid >> 6;
  const int l15 = lane & 15, grp = lane >> 4;

  __shared__ alignas(16) char smem[SMEM_SZ];
  char* gB  = smem + G_OFF;
  u16* rwq = (u16*)(smem + RWQ_OFF);
  u16* rrq = (u16*)(smem + RRQ_OFF);
  float* redf = (float*)(smem + RED_OFF);

  // ---- Phase A: rw_q (32) + rr_q (48) rows, bias, prescale 0.125*log2e
  const float PRESCALE = 0.125f * 1.44269504089f;
#pragma unroll
  for (int rep = 0; rep < 2; ++rep){
    int c = tid + rep * 512;
    if (c < 640){
      int s = c >> 3, sg = c & 7;
      u16* dst; int row; const float* bias;
      if (s < 32){ dst = rwq; row = s; bias = rwb; }
      else       { dst = rrq; row = s - 32; bias = rrb; }
      int qrow = q0 + row;
      float v[8];
      const float* bp2 = bias + head * 64 + sg * 8;
      if (qrow < T_){
        const u16* qp = qkv + ((size_t)qrow * 8 + bat) * N3_ + head * 192 + sg * 8;
        us8 qv = *(const us8*)qp;
        f4 b0 = *(const f4*)bp2, b1 = *(const f4*)(bp2 + 4);
#pragma unroll
        for (int u = 0; u < 4; ++u){
          v[u]     = (b2f(qv[u])     + b0[u]) * PRESCALE;
          v[u + 4] = (b2f(qv[u + 4]) + b1[u]) * PRESCALE;
        }
      } else {
#pragma unroll
        for (int u = 0; u < 8; ++u) v[u] = 0.f;
      }
      us8 pk;
#pragma unroll
      for (int u = 0; u < 8; ++u) pk[u] = f2b(v[u]);
      *(us8*)((char*)dst + row * 128 + ((sg * 16) ^ ((row & 7) << 4))) = pk;
    }
  }
  if (tid < 33) *(u16*)(gB + tid * 2050 + 2048) = 0;

  auto ldf = [&](const void* base, int row, int kkb)->short8 {
    int co = kkb + (grp << 4);
    return *(const short8*)((const char*)base + row * 128 + (co ^ ((row & 7) << 4)));
  };

  __syncthreads();                 // (1) Phase A + zero slots

  // ---- Phase B: g[a][r] = rr_q[q0+a].rk[r], a<33 (flat-1025 store, plain addressing)
  {
    short8 af[3][2];
#pragma unroll
    for (int pi = 0; pi < 3; ++pi)
#pragma unroll
      for (int kk = 0; kk < 2; ++kk) af[pi][kk] = ldf(rrq, pi * 16 + l15, kk * 64);
    const int sbase = (grp * 4) * 2050 + ((wave * 64 + l15) << 1);
#pragma unroll
    for (int s = 0; s < 2; ++s){
#pragma unroll
      for (int c4 = 0; c4 < 4; ++c4){
        int r = s * 512 + wave * 64 + c4 * 16 + l15;
        const u16* bp = rk + ((size_t)r * 8 + bat) * 1024 + head * 64 + grp * 8;
        short8 bf0 = *(const short8*)bp;
        short8 bf1 = *(const short8*)(bp + 32);
#pragma unroll
        for (int pi = 0; pi < 3; ++pi){
          f32x4 acc = {0.f, 0.f, 0.f, 0.f};
          acc = __builtin_amdgcn_mfma_f32_16x16x32_bf16(af[pi][0], bf0, acc, 0, 0, 0);
          acc = __builtin_amdgcn_mfma_f32_16x16x32_bf16(af[pi][1], bf1, acc, 0, 0, 0);
#pragma unroll
          for (int jj = 0; jj < 4; ++jj){
            int a = pi * 16 + (grp << 2) + jj;
            if (a < 33)
              *(u16*)(gB + sbase + (pi * 16 + jj) * 2050 + ((s * 512 + c4 * 16) << 1)) = f2b(acc[jj]);
          }
        }
      }
    }
  }
  __syncthreads();                 // (2) gS complete — last barrier before epilogue

  // ---- Q fragments (B-operand of swapped QK)
  short8 qf[2][2];
#pragma unroll
  for (int m = 0; m < 2; ++m)
#pragma unroll
    for (int kk = 0; kk < 2; ++kk) qf[m][kk] = ldf(rwq, m * 16 + l15, kk * 64);

  float m_run[2] = {-3.0e38f, -3.0e38f};
  float l_run[2] = {0.f, 0.f};
  f32x4 Oacc[2][4] = {};

  // per-thread gather base: byte = aa*2048 + (1023-q0+bcol)*2 ; aa = m*16+l15
  const int gthr = (l15 << 11) + ((1023 - q0 + wave * 64 + (grp << 2)) << 1);

#pragma unroll
  for (int pr = 0; pr < 4; ++pr){
    int base = wave * 64 + (pr & 1) * 32 + (pr >> 1) * 512;
    float s_[2][2][4];
#pragma unroll
    for (int h = 0; h < 2; ++h){
      int cb = base + h * 16;
      const u16* kp = qkv + ((size_t)(cb + l15) * 8 + bat) * N3_ + head * 192 + 64 + grp * 8;
      short8 kf0 = *(const short8*)kp;
      short8 kf1 = *(const short8*)(kp + 32);
#pragma unroll
      for (int m = 0; m < 2; ++m){
        f32x4 acc = {0.f, 0.f, 0.f, 0.f};
        acc = __builtin_amdgcn_mfma_f32_16x16x32_bf16(kf0, qf[m][0], acc, 0, 0, 0);
        acc = __builtin_amdgcn_mfma_f32_16x16x32_bf16(kf1, qf[m][1], acc, 0, 0, 0);
#pragma unroll
        for (int jj = 0; jj < 4; ++jj){
          int off = (m << 15) + (((pr & 1) * 32 + (pr >> 1) * 512 + h * 16 + jj) << 1);
          s_[h][m][jj] = acc[jj] + b2f(*(const u16*)(gB + gthr + off));
        }
      }
    }
    float cm[2];
#pragma unroll
    for (int m = 0; m < 2; ++m){
      float c0 = fmaxf(fmaxf(s_[0][m][0], s_[0][m][1]), fmaxf(s_[0][m][2], s_[0][m][3]));
      float c1 = fmaxf(fmaxf(s_[1][m][0], s_[1][m][1]), fmaxf(s_[1][m][2], s_[1][m][3]));
      float c = fmaxf(c0, c1);
      c = fmaxf(c, __shfl_xor(c, 16));
      c = fmaxf(c, __shfl_xor(c, 32));
      cm[m] = c;
    }
    if (!__all(cm[0] <= m_run[0] + 8.f && cm[1] <= m_run[1] + 8.f)){
#pragma unroll
      for (int m = 0; m < 2; ++m){
        float mn = fmaxf(m_run[m], cm[m]);
        float f = __builtin_exp2f(m_run[m] - mn);
        l_run[m] *= f;
        m_run[m] = mn;
#pragma unroll
        for (int jj = 0; jj < 4; ++jj){
          float fq = __shfl(f, (lane & 48) + ((lane >> 2) & 12) + jj);
#pragma unroll
          for (int dt = 0; dt < 4; ++dt) Oacc[m][dt][jj] *= fq;
        }
      }
    }
    short8 pa[2];
#pragma unroll
    for (int m = 0; m < 2; ++m){
      float ls = 0.f;
#pragma unroll
      for (int jj = 0; jj < 4; ++jj){
        float e0 = __builtin_exp2f(s_[0][m][jj] - m_run[m]);
        float e1 = __builtin_exp2f(s_[1][m][jj] - m_run[m]);
        ls += e0 + e1;
        pa[m][jj]     = (short)f2b(e0);
        pa[m][4 + jj] = (short)f2b(e1);
      }
      l_run[m] += ls;
    }
#pragma unroll
    for (int dt = 0; dt < 4; ++dt){
      const u16* vp = VTg + ((size_t)n * 64 + dt * 16 + l15) * 1024 + base + (grp << 2);
      short8 vb;
      *(short4v*)&vb = *(const short4v*)vp;
      *((short4v*)&vb + 1) = *(const short4v*)(vp + 16);
#pragma unroll
      for (int m = 0; m < 2; ++m)
        Oacc[m][dt] = __builtin_amdgcn_mfma_f32_16x16x32_bf16(pa[m], vb, Oacc[m][dt], 0, 0, 0);
    }
  }

#pragma unroll
  for (int m = 0; m < 2; ++m){
    l_run[m] += __shfl_xor(l_run[m], 16);
    l_run[m] += __shfl_xor(l_run[m], 32);
  }
  if (grp == 0){
#pragma unroll
    for (int m = 0; m < 2; ++m){
      redf[wave * 32 + m * 16 + l15] = m_run[m];
      redf[256 + wave * 32 + m * 16 + l15] = l_run[m];
    }
  }
  __syncthreads();                 // (3) all gS gathers done -> partials overlay gS

  float* par = (float*)(smem + wave * 8192);
#pragma unroll
  for (int m = 0; m < 2; ++m)
#pragma unroll
    for (int dt = 0; dt < 4; ++dt)
#pragma unroll
      for (int jj = 0; jj < 4; ++jj)
        par[(m * 16 + (grp << 2) + jj) * 64 + dt * 16 + l15] = Oacc[m][dt][jj];
  __syncthreads();                 // (4) partials + redf visible

  {
    float* parAll = (float*)smem;
    int q = tid >> 4, d4 = (tid & 15) * 4;
    float M = -3.0e38f;
#pragma unroll
    for (int w = 0; w < 8; ++w) M = fmaxf(M, redf[w * 32 + q]);
    f32x4 v = {0.f, 0.f, 0.f, 0.f};
    float L = 0.f;
#pragma unroll
    for (int w = 0; w < 8; ++w){
      float sc = __builtin_exp2f(redf[w * 32 + q] - M);
      L += redf[256 + w * 32 + q] * sc;
      f32x4 pv = *(const f32x4*)(parAll + w * 2048 + q * 64 + d4);
      v += pv * sc;
    }
    float il = 1.0f / (L + 1e-20f);
    us4 pk;
#pragma unroll
    for (int e = 0; e < 4; ++e) pk[e] = f2b(v[e] * il);
    *(us4*)(ctx + ((size_t)(q0 + q) * 8 + bat) * 1024 + head * 64 + d4) = pk;
  }
}

// ---------------- launch ----------------
extern "C" void kernel_launch(void* const* d_in, const int* in_sizes, int n_in,
                              void* d_out, int out_size, void* d_ws, size_t ws_size,
                              hipStream_t stream){
  const float* x   = (const float*)d_in[0];
  const float* pos = (const float*)d_in[1];
  const float* Wi  = (const float*)d_in[2];
  const float* bi  = (const float*)d_in[3];
  const float* Wp  = (const float*)d_in[4];
  const float* bp  = (const float*)d_in[5];
  const float* Wo  = (const float*)d_in[6];
  const float* bo  = (const float*)d_in[7];
  const float* r_i = (const float*)d_in[8];
  const float* s_i = (const float*)d_in[9];
  const float* r_p = (const float*)d_in[10];
  const float* s_p = (const float*)d_in[11];
  const float* rwb = (const float*)d_in[12];
  const float* rrb = (const float*)d_in[13];

  const size_t MB = 1024 * 1024;
  u16* qkv = (u16*)((char*)d_ws);              // 48 MiB (bf16)
  u16* rk  = (u16*)((char*)d_ws + 48 * MB);    // 16 MiB (bf16); ws total 64 MiB
  // d_out scratch: [0:16.78M) = Ai (pre-scaled bf16 x), later VT; [16.78M:33.55M) = ctx
  u16* Ai   = (u16*)d_out;
  u16* VTg  = (u16*)d_out;
  u16* ctxg = (u16*)((char*)d_out + 16777216);

  k_scaleA<<<dim3(4096), 256, 0, stream>>>(x, r_i, Ai);
  k_gemm<true,  false, false, true,  false><<<dim3(24, 64), 256, 0, stream>>>(Ai,  Wi, nullptr, s_i, bi, qkv, N3_);
  k_gemm<true,  true,  true,  false, false><<<dim3(8, 64),  256, 0, stream>>>(pos, Wp, r_p,    s_p, bp, rk, 1024);
  k_vt<<<dim3(16, 128), 256, 0, stream>>>(qkv, VTg);
  k_attn<<<dim3(4096), 512, 0, stream>>>(qkv, rk, VTg, rwb, rrb, ctxg);
  hipMemcpyAsync(qkv, ctxg, (size_t)out_size * sizeof(u16), hipMemcpyDeviceToDevice, stream);
  k_gemm<false, false, false, true,  true ><<<dim3(8, 64),  256, 0, stream>>>(qkv, Wo, nullptr, nullptr, bo, (float*)d_out, 1024);
}

// Round 14
// 439.826 us; speedup vs baseline: 1.2855x; 1.0161x over previous
//
#include <hip/hip_runtime.h>
#include <cstdint>
#include <cstddef>

using u16 = unsigned short;
typedef short short8 __attribute__((ext_vector_type(8)));
typedef short short4v __attribute__((ext_vector_type(4)));
typedef unsigned short us8 __attribute__((ext_vector_type(8)));
typedef unsigned short us4 __attribute__((ext_vector_type(4)));
typedef float f32x4 __attribute__((ext_vector_type(4)));
typedef float f4 __attribute__((ext_vector_type(4)));

#define T_ 1024
#define B_ 8
#define H_ 1024
#define HEADS_ 16
#define HD_ 64
#define N3_ 3072

__device__ __forceinline__ float b2f(u16 u){
  union { float f; unsigned int i; } v; v.i = ((unsigned int)u) << 16; return v.f;
}
__device__ __forceinline__ u16 f2b(float f){
  union { float f; unsigned int i; } v; v.f = f;
  return (u16)((v.i + 0x8000u) >> 16);
}
typedef __attribute__((address_space(1))) const void gvoid;
typedef __attribute__((address_space(3))) void lvoid;
__device__ __forceinline__ void gload16(const void* g, void* l){
  __builtin_amdgcn_global_load_lds((gvoid*)g, (lvoid*)l, 16, 0, 0);
}

// ---------------- pre-scale+convert: Ai[m][k] = bf16(x[m][k] * r[m&7][k]) ----------------
__global__ __launch_bounds__(256) void k_scaleA(const float* __restrict__ x, const float* __restrict__ r,
                                                u16* __restrict__ o){
  int idx = blockIdx.x * 256 + threadIdx.x;
  int base = idx * 8;
  int h = base & (H_ - 1);
  int b = (base >> 10) & (B_ - 1);
  f4 x0 = *(const f4*)(x + base), x1 = *(const f4*)(x + base + 4);
  f4 r0 = *(const f4*)(r + b * H_ + h), r1 = *(const f4*)(r + b * H_ + h + 4);
  us8 ov;
#pragma unroll
  for (int u = 0; u < 4; ++u){ ov[u] = f2b(x0[u] * r0[u]); ov[u + 4] = f2b(x1[u] * r1[u]); }
  *(us8*)(o + base) = ov;
}

// ---------------- GEMM ----------------
template<bool HAS_S, bool SCALE_A, bool POS_A, bool A_BF16, bool OUT_F32>
__global__ __launch_bounds__(256) void k_gemm(const void* __restrict__ A_, const float* __restrict__ W,
                                              const float* __restrict__ RA, const float* __restrict__ S,
                                              const float* __restrict__ bias, void* __restrict__ C_, int N){
  const int K = 1024;
  const int n0 = blockIdx.x * 128, m0 = blockIdx.y * 128;
  const int tid = threadIdx.x, lane = tid & 63;
  const int wave = tid >> 6, wr = wave >> 1, wc = wave & 1;
  __shared__ alignas(16) u16 At[128 * 32];
  __shared__ alignas(16) u16 Bt[128 * 32];
  f32x4 acc[4][4] = {};

  for (int kt = 0; kt < 32; ++kt){
    const int k0 = kt * 32;
    f4 wv[4];
    f4 avf[4];
#pragma unroll
    for (int i = 0; i < 4; ++i){
      int c = tid + i * 256, r = c >> 3, sg = c & 7;
      wv[i] = *(const f4*)(W + (size_t)(n0 + r) * K + k0 + sg * 4);
    }
    if (!A_BF16){
      const float* A = (const float*)A_;
#pragma unroll
      for (int i = 0; i < 4; ++i){
        int c = tid + i * 256, r = c >> 3, sg = c & 7;
        int m = m0 + r;
        const float* ap = POS_A ? (A + (size_t)(m >> 3) * K + k0 + sg * 4)
                                : (A + (size_t)m * K + k0 + sg * 4);
        avf[i] = *(const f4*)ap;
        if (SCALE_A){
          f4 rv = *(const f4*)(RA + (m & 7) * K + k0 + sg * 4);
          avf[i] = avf[i] * rv;
        }
      }
    }
    __syncthreads();
    if (A_BF16){
      const u16* A = (const u16*)A_;
#pragma unroll
      for (int i = 0; i < 2; ++i){
        int c = tid + i * 256, r = c >> 2, sg = c & 3;
        gload16(A + (size_t)(m0 + r) * K + k0 + sg * 8, (char*)At + (size_t)c * 16);
      }
    }
#pragma unroll
    for (int i = 0; i < 4; ++i){
      int c = tid + i * 256, r = c >> 3, sg = c & 7;
      us4 pw;
#pragma unroll
      for (int u = 0; u < 4; ++u) pw[u] = f2b(wv[i][u]);
      *(us4*)(Bt + r * 32 + sg * 4) = pw;
    }
    if (!A_BF16){
#pragma unroll
      for (int i = 0; i < 4; ++i){
        int c = tid + i * 256, r = c >> 3, sg = c & 7;
        us4 pa;
#pragma unroll
        for (int u = 0; u < 4; ++u) pa[u] = f2b(avf[i][u]);
        *(us4*)(At + r * 32 + sg * 4) = pa;
      }
    }
    __syncthreads();
    short8 af[4], bf[4];
#pragma unroll
    for (int i = 0; i < 4; ++i){
      int ar = wr * 64 + i * 16 + (lane & 15);
      af[i] = *(const short8*)(At + ar * 32 + ((lane >> 4) << 3));
      int br = wc * 64 + i * 16 + (lane & 15);
      bf[i] = *(const short8*)(Bt + br * 32 + ((lane >> 4) << 3));
    }
#pragma unroll
    for (int i = 0; i < 4; ++i)
#pragma unroll
      for (int j = 0; j < 4; ++j)
        acc[i][j] = __builtin_amdgcn_mfma_f32_16x16x32_bf16(af[i], bf[j], acc[i][j], 0, 0, 0);
  }
#pragma unroll
  for (int i = 0; i < 4; ++i){
    int row0 = wr * 64 + i * 16 + ((lane >> 4) << 2);
#pragma unroll
    for (int j = 0; j < 4; ++j){
      int o = n0 + wc * 64 + j * 16 + (lane & 15);
      float bv = bias[o];
#pragma unroll
      for (int jj = 0; jj < 4; ++jj){
        int m = m0 + row0 + jj;
        float v = acc[i][j][jj];
        if (HAS_S) v *= S[(m & 7) * N + o];
        v += bv;
        if (OUT_F32) ((float*)C_)[(size_t)m * N + o] = v;
        else         ((u16*)C_)[(size_t)m * N + o] = f2b(v);
      }
    }
  }
}

// ---------------- V transpose to global: VT[n][d][t] <- qkv[t, b, head*192+128+d] ----------------
__global__ __launch_bounds__(256) void k_vt(const u16* __restrict__ qkv, u16* __restrict__ VT){
  const int tt = blockIdx.x;
  const int n = blockIdx.y;
  const int b = n >> 4, head = n & 15;
  __shared__ alignas(16) u16 tile[64][72];
  const int tid = threadIdx.x;
#pragma unroll
  for (int i = 0; i < 2; ++i){
    int c = tid + i * 256;
    int r = c >> 3, sg = c & 7;
    const u16* src = qkv + ((size_t)(tt * 64 + r) * 8 + b) * N3_ + head * 192 + 128 + sg * 8;
    *(us8*)&tile[r][sg * 8] = *(const us8*)src;
  }
  __syncthreads();
#pragma unroll
  for (int i = 0; i < 2; ++i){
    int c = tid + i * 256;
    int d = c >> 3, sg = c & 7;
    us8 ov;
#pragma unroll
    for (int u = 0; u < 8; ++u) ov[u] = tile[sg * 8 + u][d];
    *(us8*)(VT + ((size_t)n * 64 + d) * 1024 + tt * 64 + sg * 8) = ov;
  }
}

// ---------------- fused attention: q32, per-wave online softmax, swapped QK ----------------
// waves_per_eu(4,4): pin register budget to exactly 128 (r13's min-only form let the
// compiler squeeze to 64 VGPR and spill ~5MB scratch into the critical chain).
#define G_OFF   0           // flat g: 33*1025*2 = 67650 B; epilogue: per-wave f32 partials (8x8KB)
#define RWQ_OFF 67664       // 32 x 128B
#define RRQ_OFF 71760       // 48 x 128B
#define RED_OFF 77904       // 512 floats: per-wave row m / row l
#define SMEM_SZ 79952

__global__ __launch_bounds__(512) __attribute__((amdgpu_waves_per_eu(4, 4)))
void k_attn(const u16* __restrict__ qkv, const u16* __restrict__ rk,
            const u16* __restrict__ VTg, const float* __restrict__ rwb,
            const float* __restrict__ rrb, u16* __restrict__ ctx){
  const int bid = blockIdx.x;
  const int n = (bid & 7) + ((bid >> 8) << 3);
  const int qb = (bid >> 3) & 31;
  const int q0 = qb * 32;
  const int bat = n >> 4, head = n & 15;
  const int tid = threadIdx.x, lane = tid & 63, wave = tid >> 6;
  const int l15 = lane & 15, grp = lane >> 4;

  __shared__ alignas(16) char smem[SMEM_SZ];
  char* gB  = smem + G_OFF;
  u16* rwq = (u16*)(smem + RWQ_OFF);
  u16* rrq = (u16*)(smem + RRQ_OFF);
  float* redf = (float*)(smem + RED_OFF);

  // ---- Phase A: rw_q (32) + rr_q (48) rows, bias, prescale 0.125*log2e
  const float PRESCALE = 0.125f * 1.44269504089f;
#pragma unroll
  for (int rep = 0; rep < 2; ++rep){
    int c = tid + rep * 512;
    if (c < 640){
      int s = c >> 3, sg = c & 7;
      u16* dst; int row; const float* bias;
      if (s < 32){ dst = rwq; row = s; bias = rwb; }
      else       { dst = rrq; row = s - 32; bias = rrb; }
      int qrow = q0 + row;
      float v[8];
      const float* bp2 = bias + head * 64 + sg * 8;
      if (qrow < T_){
        const u16* qp = qkv + ((size_t)qrow * 8 + bat) * N3_ + head * 192 + sg * 8;
        us8 qv = *(const us8*)qp;
        f4 b0 = *(const f4*)bp2, b1 = *(const f4*)(bp2 + 4);
#pragma unroll
        for (int u = 0; u < 4; ++u){
          v[u]     = (b2f(qv[u])     + b0[u]) * PRESCALE;
          v[u + 4] = (b2f(qv[u + 4]) + b1[u]) * PRESCALE;
        }
      } else {
#pragma unroll
        for (int u = 0; u < 8; ++u) v[u] = 0.f;
      }
      us8 pk;
#pragma unroll
      for (int u = 0; u < 8; ++u) pk[u] = f2b(v[u]);
      *(us8*)((char*)dst + row * 128 + ((sg * 16) ^ ((row & 7) << 4))) = pk;
    }
  }
  if (tid < 33) *(u16*)(gB + tid * 2050 + 2048) = 0;

  auto ldf = [&](const void* base, int row, int kkb)->short8 {
    int co = kkb + (grp << 4);
    return *(const short8*)((const char*)base + row * 128 + (co ^ ((row & 7) << 4)));
  };

  __syncthreads();                 // (1) Phase A + zero slots

  // ---- Phase B: g[a][r] = rr_q[q0+a].rk[r], a<33 (flat-1025 store, plain addressing)
  {
    short8 af[3][2];
#pragma unroll
    for (int pi = 0; pi < 3; ++pi)
#pragma unroll
      for (int kk = 0; kk < 2; ++kk) af[pi][kk] = ldf(rrq, pi * 16 + l15, kk * 64);
    const int sbase = (grp * 4) * 2050 + ((wave * 64 + l15) << 1);
#pragma unroll
    for (int s = 0; s < 2; ++s){
#pragma unroll
      for (int c4 = 0; c4 < 4; ++c4){
        int r = s * 512 + wave * 64 + c4 * 16 + l15;
        const u16* bp = rk + ((size_t)r * 8 + bat) * 1024 + head * 64 + grp * 8;
        short8 bf0 = *(const short8*)bp;
        short8 bf1 = *(const short8*)(bp + 32);
        __builtin_amdgcn_s_setprio(1);
#pragma unroll
        for (int pi = 0; pi < 3; ++pi){
          f32x4 acc = {0.f, 0.f, 0.f, 0.f};
          acc = __builtin_amdgcn_mfma_f32_16x16x32_bf16(af[pi][0], bf0, acc, 0, 0, 0);
          acc = __builtin_amdgcn_mfma_f32_16x16x32_bf16(af[pi][1], bf1, acc, 0, 0, 0);
#pragma unroll
          for (int jj = 0; jj < 4; ++jj){
            int a = pi * 16 + (grp << 2) + jj;
            if (a < 33)
              *(u16*)(gB + sbase + (pi * 16 + jj) * 2050 + ((s * 512 + c4 * 16) << 1)) = f2b(acc[jj]);
          }
        }
        __builtin_amdgcn_s_setprio(0);
      }
    }
  }
  __syncthreads();                 // (2) gS complete — last barrier before epilogue

  // ---- Q fragments (B-operand of swapped QK)
  short8 qf[2][2];
#pragma unroll
  for (int m = 0; m < 2; ++m)
#pragma unroll
    for (int kk = 0; kk < 2; ++kk) qf[m][kk] = ldf(rwq, m * 16 + l15, kk * 64);

  float m_run[2] = {-3.0e38f, -3.0e38f};
  float l_run[2] = {0.f, 0.f};
  f32x4 Oacc[2][4] = {};

  // per-thread gather base: byte = aa*2048 + (1023-q0+bcol)*2 ; aa = m*16+l15
  const int gthr = (l15 << 11) + ((1023 - q0 + wave * 64 + (grp << 2)) << 1);

#pragma unroll
  for (int pr = 0; pr < 4; ++pr){
    int base = wave * 64 + (pr & 1) * 32 + (pr >> 1) * 512;
    // ---- issue ALL loads for this pr up front (K for both halves, V for all dt)
    short8 kf[2][2];
#pragma unroll
    for (int h = 0; h < 2; ++h){
      const u16* kp = qkv + ((size_t)(base + h * 16 + l15) * 8 + bat) * N3_ + head * 192 + 64 + grp * 8;
      kf[h][0] = *(const short8*)kp;
      kf[h][1] = *(const short8*)(kp + 32);
    }
    short8 vb[4];
#pragma unroll
    for (int dt = 0; dt < 4; ++dt){
      const u16* vp = VTg + ((size_t)n * 64 + dt * 16 + l15) * 1024 + base + (grp << 2);
      *(short4v*)&vb[dt] = *(const short4v*)vp;
      *((short4v*)&vb[dt] + 1) = *(const short4v*)(vp + 16);
    }
    // ---- QK^T (swapped) + rel-shift gather
    float s_[2][2][4];
#pragma unroll
    for (int h = 0; h < 2; ++h){
      __builtin_amdgcn_s_setprio(1);
      f32x4 acc0 = {0.f, 0.f, 0.f, 0.f}, acc1 = {0.f, 0.f, 0.f, 0.f};
      acc0 = __builtin_amdgcn_mfma_f32_16x16x32_bf16(kf[h][0], qf[0][0], acc0, 0, 0, 0);
      acc0 = __builtin_amdgcn_mfma_f32_16x16x32_bf16(kf[h][1], qf[0][1], acc0, 0, 0, 0);
      acc1 = __builtin_amdgcn_mfma_f32_16x16x32_bf16(kf[h][0], qf[1][0], acc1, 0, 0, 0);
      acc1 = __builtin_amdgcn_mfma_f32_16x16x32_bf16(kf[h][1], qf[1][1], acc1, 0, 0, 0);
      __builtin_amdgcn_s_setprio(0);
#pragma unroll
      for (int jj = 0; jj < 4; ++jj){
        int coff = (((pr & 1) * 32 + (pr >> 1) * 512 + h * 16 + jj) << 1);
        s_[h][0][jj] = acc0[jj] + b2f(*(const u16*)(gB + gthr + coff));
        s_[h][1][jj] = acc1[jj] + b2f(*(const u16*)(gB + gthr + (1 << 15) + coff));
      }
    }
    // ---- pair max per q-row
    float cm[2];
#pragma unroll
    for (int m = 0; m < 2; ++m){
      float c0 = fmaxf(fmaxf(s_[0][m][0], s_[0][m][1]), fmaxf(s_[0][m][2], s_[0][m][3]));
      float c1 = fmaxf(fmaxf(s_[1][m][0], s_[1][m][1]), fmaxf(s_[1][m][2], s_[1][m][3]));
      float c = fmaxf(c0, c1);
      c = fmaxf(c, __shfl_xor(c, 16));
      c = fmaxf(c, __shfl_xor(c, 32));
      cm[m] = c;
    }
    // ---- defer-max rescale (rare)
    if (!__all(cm[0] <= m_run[0] + 8.f && cm[1] <= m_run[1] + 8.f)){
#pragma unroll
      for (int m = 0; m < 2; ++m){
        float mn = fmaxf(m_run[m], cm[m]);
        float f = __builtin_exp2f(m_run[m] - mn);
        l_run[m] *= f;
        m_run[m] = mn;
#pragma unroll
        for (int jj = 0; jj < 4; ++jj){
          float fq = __shfl(f, (lane & 48) + ((lane >> 2) & 12) + jj);
#pragma unroll
          for (int dt = 0; dt < 4; ++dt) Oacc[m][dt][jj] *= fq;
        }
      }
    }
    // ---- exp2, l accumulate, pack P pair
    short8 pa[2];
#pragma unroll
    for (int m = 0; m < 2; ++m){
      float ls = 0.f;
#pragma unroll
      for (int jj = 0; jj < 4; ++jj){
        float e0 = __builtin_exp2f(s_[0][m][jj] - m_run[m]);
        float e1 = __builtin_exp2f(s_[1][m][jj] - m_run[m]);
        ls += e0 + e1;
        pa[m][jj]     = (short)f2b(e0);
        pa[m][4 + jj] = (short)f2b(e1);
      }
      l_run[m] += ls;
    }
    // ---- PV with preloaded V
    __builtin_amdgcn_s_setprio(1);
#pragma unroll
    for (int dt = 0; dt < 4; ++dt)
#pragma unroll
      for (int m = 0; m < 2; ++m)
        Oacc[m][dt] = __builtin_amdgcn_mfma_f32_16x16x32_bf16(pa[m], vb[dt], Oacc[m][dt], 0, 0, 0);
    __builtin_amdgcn_s_setprio(0);
  }

#pragma unroll
  for (int m = 0; m < 2; ++m){
    l_run[m] += __shfl_xor(l_run[m], 16);
    l_run[m] += __shfl_xor(l_run[m], 32);
  }
  if (grp == 0){
#pragma unroll
    for (int m = 0; m < 2; ++m){
      redf[wave * 32 + m * 16 + l15] = m_run[m];
      redf[256 + wave * 32 + m * 16 + l15] = l_run[m];
    }
  }
  __syncthreads();                 // (3) all gS gathers done -> partials overlay gS

  float* par = (float*)(smem + wave * 8192);
#pragma unroll
  for (int m = 0; m < 2; ++m)
#pragma unroll
    for (int dt = 0; dt < 4; ++dt)
#pragma unroll
      for (int jj = 0; jj < 4; ++jj)
        par[(m * 16 + (grp << 2) + jj) * 64 + dt * 16 + l15] = Oacc[m][dt][jj];
  __syncthreads();                 // (4) partials + redf visible

  {
    float* parAll = (float*)smem;
    int q = tid >> 4, d4 = (tid & 15) * 4;
    float M = -3.0e38f;
#pragma unroll
    for (int w = 0; w < 8; ++w) M = fmaxf(M, redf[w * 32 + q]);
    f32x4 v = {0.f, 0.f, 0.f, 0.f};
    float L = 0.f;
#pragma unroll
    for (int w = 0; w < 8; ++w){
      float sc = __builtin_exp2f(redf[w * 32 + q] - M);
      L += redf[256 + w * 32 + q] * sc;
      f32x4 pv = *(const f32x4*)(parAll + w * 2048 + q * 64 + d4);
      v += pv * sc;
    }
    float il = 1.0f / (L + 1e-20f);
    us4 pk;
#pragma unroll
    for (int e = 0; e < 4; ++e) pk[e] = f2b(v[e] * il);
    *(us4*)(ctx + ((size_t)(q0 + q) * 8 + bat) * 1024 + head * 64 + d4) = pk;
  }
}

// ---------------- launch ----------------
extern "C" void kernel_launch(void* const* d_in, const int* in_sizes, int n_in,
                              void* d_out, int out_size, void* d_ws, size_t ws_size,
                              hipStream_t stream){
  const float* x   = (const float*)d_in[0];
  const float* pos = (const float*)d_in[1];
  const float* Wi  = (const float*)d_in[2];
  const float* bi  = (const float*)d_in[3];
  const float* Wp  = (const float*)d_in[4];
  const float* bp  = (const float*)d_in[5];
  const float* Wo  = (const float*)d_in[6];
  const float* bo  = (const float*)d_in[7];
  const float* r_i = (const float*)d_in[8];
  const float* s_i = (const float*)d_in[9];
  const float* r_p = (const float*)d_in[10];
  const float* s_p = (const float*)d_in[11];
  const float* rwb = (const float*)d_in[12];
  const float* rrb = (const float*)d_in[13];

  const size_t MB = 1024 * 1024;
  u16* qkv = (u16*)((char*)d_ws);              // 48 MiB (bf16)
  u16* rk  = (u16*)((char*)d_ws + 48 * MB);    // 16 MiB (bf16); ws total 64 MiB
  u16* Ai   = (u16*)d_out;
  u16* VTg  = (u16*)d_out;
  u16* ctxg = (u16*)((char*)d_out + 16777216);

  k_scaleA<<<dim3(4096), 256, 0, stream>>>(x, r_i, Ai);
  k_gemm<true,  false, false, true,  false><<<dim3(24, 64), 256, 0, stream>>>(Ai,  Wi, nullptr, s_i, bi, qkv, N3_);
  k_gemm<true,  true,  true,  false, false><<<dim3(8, 64),  256, 0, stream>>>(pos, Wp, r_p,    s_p, bp, rk, 1024);
  k_vt<<<dim3(16, 128), 256, 0, stream>>>(qkv, VTg);
  k_attn<<<dim3(4096), 512, 0, stream>>>(qkv, rk, VTg, rwb, rrb, ctxg);
  hipMemcpyAsync(qkv, ctxg, (size_t)out_size * sizeof(u16), hipMemcpyDeviceToDevice, stream);
  k_gemm<false, false, false, true,  true ><<<dim3(8, 64),  256, 0, stream>>>(qkv, Wo, nullptr, nullptr, bo, (float*)d_out, 1024);
}